// Round 12
// baseline (300.020 us; speedup 1.0000x reference)
//
#include <hip/hip_runtime.h>

#define FD 128      // feature dim (both layers)
#define BSH 7       // log2(nodes per bucket) = 128 nodes/bucket
#define CH 4096     // edges per partition block (391 blocks)
#define CHT 16      // edges per thread (CH / 256)
#define KMAX 512    // max buckets
#define SCAP 8192   // build_kernel LDS edge stage (mean bucket = 4092, max ~4400)
#define DB 128      // deg-histogram blocks fused into partition launch
// packed pair: (local_dst << 17) | src   -- requires N <= 131072

typedef __attribute__((ext_vector_type(8))) short bf16x8;
typedef __attribute__((ext_vector_type(4))) float f32x4;

__device__ inline unsigned bfr(float f) {   // fp32 -> bf16 bits, round-nearest-even
    unsigned u = __float_as_uint(f);
    return (u + 0x7FFF + ((u >> 16) & 1)) >> 16;
}
__device__ inline float uplo(unsigned p) { return __uint_as_float(p << 16); }
__device__ inline float uphi(unsigned p) { return __uint_as_float(p & 0xFFFF0000u); }

// ---------------- CSR build ----------------
// R12: dependency-broken pipeline. dis needs only the dst-degree histogram,
// so deg is computed via global atomics fused into the partition launch;
// deg->dis and the weight transpose ride the trtot launch; gemm1 then merges
// into the build launch (fat kernel, aliased LDS) and hides under build.
// All numerics bit-identical to R11 (same dis, h', agg). 7 dispatches.

__global__ __launch_bounds__(256) void partition_kernel(
        const int* __restrict__ src, const int* __restrict__ dst,
        int* __restrict__ lstartG, int* __restrict__ total,
        int* __restrict__ pairs, int E, int K, int PB,
        int* __restrict__ deg) {
    __shared__ int lcnt[KMAX];     // counts, then scatter cursor
    __shared__ int lstart[KMAX];   // local exclusive prefix
    __shared__ int sm[256];
    __shared__ int staged[CH];
    int t = threadIdx.x;

    if ((int)blockIdx.x >= PB) {   // deg-histogram fold (DB blocks)
        int i0 = ((int)blockIdx.x - PB) * 256 + t;
        for (int i = i0; i < E; i += DB * 256)
            atomicAdd(&deg[dst[i]], 1);
        return;
    }

    int base = blockIdx.x * CH;
    int n = min(CH, E - base);

    lcnt[t] = 0; lcnt[t + 256] = 0;
    __syncthreads();

    int pk[CHT]; int bn[CHT];
    #pragma unroll
    for (int j = 0; j < CHT; ++j) {
        int i = t + j * 256;
        bn[j] = -1;
        if (i < n) {
            int d = dst[base + i];
            int s = src[base + i];
            bn[j] = d >> BSH;
            pk[j] = ((d & ((1 << BSH) - 1)) << 17) | s;
            atomicAdd(&lcnt[bn[j]], 1);
        }
    }
    __syncthreads();

    // exclusive scan of 512 bins, 2 consecutive bins per thread
    int c0 = lcnt[2 * t], c1 = lcnt[2 * t + 1];
    int s2 = c0 + c1;
    sm[t] = s2;
    __syncthreads();
    for (int off = 1; off < 256; off <<= 1) {
        int add = (t >= off) ? sm[t - off] : 0;
        __syncthreads();
        sm[t] += add;
        __syncthreads();
    }
    int ex = sm[t] - s2;
    lstart[2 * t] = ex;     lstart[2 * t + 1] = ex + c0;
    lcnt[2 * t]   = ex;     lcnt[2 * t + 1]   = ex + c0;   // cursor
    __syncthreads();

    // scatter chunk into staged[], sorted by bucket
    #pragma unroll
    for (int j = 0; j < CHT; ++j) {
        if (bn[j] >= 0) {
            int pos = atomicAdd(&lcnt[bn[j]], 1);
            staged[pos] = pk[j];
        }
    }
    __syncthreads();

    // sequential coalesced copy-out: this block owns pairs[base .. base+n)
    for (int i = t; i < n; i += 256)
        pairs[base + i] = staged[i];

    // per-block bucket boundaries + bucket totals
    size_t lrow = (size_t)blockIdx.x * (K + 1);
    for (int b = t; b < K; b += 256) {
        lstartG[lrow + b] = lstart[b];
        int c = lcnt[b] - lstart[b];
        if (c) atomicAdd(&total[b], c);
    }
    if (t == 0) lstartG[lrow + K] = n;
}

// merged launch: [0,nbt) transpose lstartG -> lstartT; block nbt = totscan;
// (nbt, nbt+ndis] = deg->dis convert; rest = weight transpose fp32->bf16.
__global__ __launch_bounds__(512) void trtot_kernel(
        const int* __restrict__ A, int* __restrict__ B, int R, int C,
        const int* __restrict__ total, int* __restrict__ bbase,
        int* __restrict__ rp, int K, int E, int N, int nbx, int nbt, int ndis,
        const int* __restrict__ deg, float* __restrict__ dis,
        const float* __restrict__ W1, unsigned short* __restrict__ W1T,
        const float* __restrict__ W2, unsigned short* __restrict__ W2T) {
    __shared__ int tile[32][33];
    int t = threadIdx.x;
    int b = blockIdx.x;
    if (b == nbt) {                              // totscan body
        __shared__ int sm[512];
        int v = (t < K) ? total[t] : 0;
        sm[t] = v;
        __syncthreads();
        for (int off = 1; off < 512; off <<= 1) {
            int add = (t >= off) ? sm[t - off] : 0;
            __syncthreads();
            sm[t] += add;
            __syncthreads();
        }
        if (t < K) bbase[t] = sm[t] - v;
        if (t == 0) { bbase[K] = E; rp[N] = E; }
        return;
    }
    if (b > nbt) {
        int i = b - nbt - 1;
        if (i < ndis) {                          // deg -> dis
            int v = i * 512 + t;
            if (v < N) dis[v] = rsqrtf((float)(deg[v] + 1));  // + self-loop
        } else {                                 // wt fold: 64 blocks x 512
            int f = (i - ndis) * 512 + t;        // flat over 2*FD*FD = 32768
            int w = f >> 14, rm = f & 16383, k = rm >> 7, nn2 = rm & 127;
            const float* W = w ? W2 : W1;
            unsigned short* WT = w ? W2T : W1T;
            WT[nn2 * FD + k] = (unsigned short)bfr(W[k * FD + nn2]);
        }
        return;
    }
    int c0 = (b % nbx) * 32, r0 = (b / nbx) * 32;
    int tx = t & 31, ty = t >> 5;                // 512 threads: ty in [0,16)
    for (int i = ty; i < 32; i += 16) {
        int r = r0 + i, c = c0 + tx;
        if (r < R && c < C) tile[i][tx] = A[(size_t)r * C + c];
    }
    __syncthreads();
    for (int i = ty; i < 32; i += 16) {
        int c = c0 + i, r = r0 + tx;
        if (c < C && r < R) B[(size_t)c * R + r] = tile[tx][i];
    }
}

// ---------------- MFMA bf16 GEMM body (shared-mem pointer passed in) -------
// R7-proven lean variant: only B staged in LDS; A fragments loaded directly
// from global (lane l16 = row, quad = k-octet -> clean 64 B sectors).

#define APAD 8
#define ASTR (FD + APAD)

template <bool A32>
__device__ void gemm_body(unsigned short* __restrict__ Bs,
                          const void* __restrict__ Ap,
                          const unsigned short* __restrict__ WT,
                          const float* __restrict__ dis,
                          unsigned short* __restrict__ C, int M, int blk) {
    int tid = threadIdx.x;
    int lane = tid & 63;
    int wave = tid >> 6;
    int quad = lane >> 4;
    int l16 = lane & 15;
    int rowBase = blk * 128;

    #pragma unroll
    for (int p = 0; p < 8; ++p) {
        int r = p * 16 + (tid >> 4);
        int cq = (tid & 15) * 8;
        *(uint4*)&Bs[r * ASTR + cq] = *(const uint4*)&WT[(size_t)r * FD + cq];
    }
    __syncthreads();

    int m0 = wave * 32;
    int r0 = rowBase + m0 + l16;        // a0 fragment row
    int r1 = r0 + 16;                   // a1 fragment row
    f32x4 acc[2][8] = {};
    #pragma unroll
    for (int kt = 0; kt < 4; ++kt) {
        int ko = kt * 32 + quad * 8;
        uint4 va = make_uint4(0u, 0u, 0u, 0u);
        uint4 vb = make_uint4(0u, 0u, 0u, 0u);
        if (A32) {
            const float* A = (const float*)Ap;
            if (r0 < M) {
                const float* a = A + (size_t)r0 * FD + ko;
                float4 f0 = *(const float4*)a;
                float4 f1 = *(const float4*)(a + 4);
                va.x = bfr(f0.x) | (bfr(f0.y) << 16);
                va.y = bfr(f0.z) | (bfr(f0.w) << 16);
                va.z = bfr(f1.x) | (bfr(f1.y) << 16);
                va.w = bfr(f1.z) | (bfr(f1.w) << 16);
            }
            if (r1 < M) {
                const float* a = A + (size_t)r1 * FD + ko;
                float4 f0 = *(const float4*)a;
                float4 f1 = *(const float4*)(a + 4);
                vb.x = bfr(f0.x) | (bfr(f0.y) << 16);
                vb.y = bfr(f0.z) | (bfr(f0.w) << 16);
                vb.z = bfr(f1.x) | (bfr(f1.y) << 16);
                vb.w = bfr(f1.z) | (bfr(f1.w) << 16);
            }
        } else {
            const unsigned short* A = (const unsigned short*)Ap;
            if (r0 < M) va = *(const uint4*)(A + (size_t)r0 * FD + ko);
            if (r1 < M) vb = *(const uint4*)(A + (size_t)r1 * FD + ko);
        }
        bf16x8 a0 = *(bf16x8*)&va;
        bf16x8 a1 = *(bf16x8*)&vb;
        #pragma unroll
        for (int n = 0; n < 8; ++n) {
            bf16x8 b = *(bf16x8*)&Bs[(n * 16 + l16) * ASTR + ko];
            acc[0][n] = __builtin_amdgcn_mfma_f32_16x16x32_bf16(a0, b, acc[0][n], 0, 0, 0);
            acc[1][n] = __builtin_amdgcn_mfma_f32_16x16x32_bf16(a1, b, acc[1][n], 0, 0, 0);
        }
    }

    #pragma unroll
    for (int ms = 0; ms < 2; ++ms) {
        #pragma unroll
        for (int r = 0; r < 4; ++r) {
            int grow = rowBase + m0 + ms * 16 + quad * 4 + r;
            if (grow < M) {
                float dv = dis[grow];
                #pragma unroll
                for (int n = 0; n < 8; ++n) {
                    C[(size_t)grow * FD + n * 16 + l16] =
                        (unsigned short)bfr(dv * acc[ms][n][r]);
                }
            }
        }
    }
}

// Fat kernel: blocks [0,K) = CSR build (fused count, per-wave planes);
// blocks [K, K+gemmGrid) = gemm1 (fp32 A path). LDS aliased (37.9 KB).
__global__ __launch_bounds__(256) void build_kernel(
        const int* __restrict__ pairs, const int* __restrict__ lstartT,
        const int* __restrict__ bbase, int* __restrict__ rp,
        int* __restrict__ col, int N, int PB, int K,
        const float* __restrict__ x, const unsigned short* __restrict__ w1t,
        const float* __restrict__ dis, unsigned short* __restrict__ hbuf) {
    __shared__ __align__(16) int smem[SCAP + 512 + 512 + 256];
    int b = blockIdx.x;
    int t = threadIdx.x;

    if (b >= K) {                // gemm1 fold
        gemm_body<true>((unsigned short*)smem, x, w1t, dis, hbuf, N, b - K);
        return;
    }

    int* staged = smem;                  // SCAP
    int* lcnt   = smem + SCAP;           // 512  [bin*4+wave]
    int* pref   = smem + SCAP + 512;     // 512
    int* sm     = smem + SCAP + 1024;    // 256

    int wv = t >> 6;
    int nbase = b << BSH;
    int nn = min(1 << BSH, N - nbase);
    int beg = bbase[b];
    int cnt = bbase[b + 1] - beg;

    // fragment descriptors (coalesced reads from transposed lstart; nf <= 2)
    int fp[2], fl0[2], flen[2];
    int nf = 0, mysum = 0;
    for (int p = t; p < PB; p += 256) {
        int l0 = lstartT[(size_t)b * PB + p];
        int l1 = lstartT[(size_t)(b + 1) * PB + p];
        fp[nf] = p; fl0[nf] = l0; flen[nf] = l1 - l0;
        mysum += l1 - l0;
        ++nf;
    }
    // exclusive scan of per-thread sums -> dest offsets in staged
    sm[t] = mysum;
    __syncthreads();
    for (int off = 1; off < 256; off <<= 1) {
        int add = (t >= off) ? sm[t - off] : 0;
        __syncthreads();
        sm[t] += add;
        __syncthreads();
    }
    int o = sm[t] - mysum;

    lcnt[t] = 0; lcnt[t + 256] = 0;
    __syncthreads();

    if (cnt <= SCAP) {   // fast path (always, for Poisson buckets)
        int oo = o;
        for (int f = 0; f < nf; ++f) {
            int gbase = fp[f] * CH + fl0[f];
            for (int i = 0; i < flen[f]; ++i) {
                int p = pairs[gbase + i];
                staged[oo + i] = p;
                atomicAdd(&lcnt[((p >> 17) << 2) | wv], 1);   // fused count
            }
            oo += flen[f];
        }
    } else {             // overflow fallback: count directly from global
        for (int f = 0; f < nf; ++f) {
            int gbase = fp[f] * CH + fl0[f];
            for (int i = 0; i < flen[f]; ++i)
                atomicAdd(&lcnt[((pairs[gbase + i] >> 17) << 2) | wv], 1);
        }
    }
    __syncthreads();

    // exclusive scan of 512 entries (bin-major: bin*4+wave), 2 per thread
    int c0 = lcnt[2 * t], c1 = lcnt[2 * t + 1];
    int s2 = c0 + c1;
    sm[t] = s2;
    __syncthreads();
    for (int off = 1; off < 256; off <<= 1) {
        int add = (t >= off) ? sm[t - off] : 0;
        __syncthreads();
        sm[t] += add;
        __syncthreads();
    }
    int ex = sm[t] - s2;
    pref[2 * t] = ex;  pref[2 * t + 1] = ex + c0;
    __syncthreads();

    // rp per row (row start = plane-0 prefix); dis now computed upstream
    if (t < 128 && t < nn) {
        int rs = pref[t << 2];
        rp[nbase + t] = beg + rs;
    }
    // cursors (absolute)
    lcnt[2 * t]     = beg + pref[2 * t];
    lcnt[2 * t + 1] = beg + pref[2 * t + 1];
    __syncthreads();

    if (cnt <= SCAP) {
        int oo = o;
        for (int f = 0; f < nf; ++f) {
            for (int i = 0; i < flen[f]; ++i) {
                int p = staged[oo + i];
                int pos = atomicAdd(&lcnt[((p >> 17) << 2) | wv], 1);
                col[pos] = p & 0x1FFFF;
            }
            oo += flen[f];
        }
    } else {
        for (int f = 0; f < nf; ++f) {
            int gbase = fp[f] * CH + fl0[f];
            for (int i = 0; i < flen[f]; ++i) {
                int p = pairs[gbase + i];
                int pos = atomicAdd(&lcnt[((p >> 17) << 2) | wv], 1);
                col[pos] = p & 0x1FFFF;
            }
        }
    }
}

__global__ __launch_bounds__(256) void gemm_mfma_bf16(
        const unsigned short* __restrict__ A, const unsigned short* __restrict__ WT,
        const float* __restrict__ dis, unsigned short* __restrict__ C, int M) {
    __shared__ __align__(16) unsigned short Bs[128 * ASTR];
    gemm_body<false>(Bs, A, WT, dis, C, M, blockIdx.x);
}

// ---------------- CSR aggregation + bias + ReLU ----------------
// Round-0 proven form (48.6 us floor, invariant across 7 designs) — UNCHANGED.

__global__ __launch_bounds__(256) void agg_kernel(
        const unsigned* __restrict__ h, const float* __restrict__ dis,
        const int* __restrict__ rp, const int* __restrict__ col,
        const float2* __restrict__ bias, void* __restrict__ out, int N, int obf) {
    int v = blockIdx.x * 4 + threadIdx.y;          // blockDim = (64, 4): wave per node
    v = __builtin_amdgcn_readfirstlane(v);         // wave-uniform -> scalar rp/col loads
    if (v >= N) return;
    int t = threadIdx.x;                           // 0..63
    float dv = dis[v];
    size_t vb = (size_t)v * 64 + t;
    unsigned hp = h[vb];                           // self term h'[v]
    float2 acc;
    acc.x = uplo(hp); acc.y = uphi(hp);
    int e = rp[v];
    int end = rp[v + 1];

    for (; e + 16 <= end; e += 16) {
        int u[16];
        #pragma unroll
        for (int j = 0; j < 16; ++j) u[j] = col[e + j];   // wave-uniform scalar loads
        unsigned p[16];
        #pragma unroll
        for (int j = 0; j < 16; ++j) p[j] = h[(size_t)u[j] * 64 + t];
        #pragma unroll
        for (int j = 0; j < 16; ++j) {
            acc.x += uplo(p[j]); acc.y += uphi(p[j]);
        }
    }
    for (; e + 4 <= end; e += 4) {
        int u0 = col[e], u1 = col[e + 1], u2 = col[e + 2], u3 = col[e + 3];
        unsigned p0 = h[(size_t)u0 * 64 + t];
        unsigned p1 = h[(size_t)u1 * 64 + t];
        unsigned p2 = h[(size_t)u2 * 64 + t];
        unsigned p3 = h[(size_t)u3 * 64 + t];
        acc.x += uplo(p0); acc.y += uphi(p0);
        acc.x += uplo(p1); acc.y += uphi(p1);
        acc.x += uplo(p2); acc.y += uphi(p2);
        acc.x += uplo(p3); acc.y += uphi(p3);
    }
    for (; e < end; ++e) {
        unsigned p = h[(size_t)col[e] * 64 + t];
        acc.x += uplo(p); acc.y += uphi(p);
    }

    float2 bb = bias[t];
    float2 r;
    r.x = fmaxf(fmaf(dv, acc.x, bb.x), 0.0f);
    r.y = fmaxf(fmaf(dv, acc.y, bb.y), 0.0f);
    if (obf) {
        ((unsigned*)out)[vb] = bfr(r.x) | (bfr(r.y) << 16);
    } else {
        ((float2*)out)[vb] = r;
    }
}

// ---------------- launch ----------------

extern "C" void kernel_launch(void* const* d_in, const int* in_sizes, int n_in,
                              void* d_out, int out_size, void* d_ws, size_t ws_size,
                              hipStream_t stream) {
    const float* x  = (const float*)d_in[0];
    const int*   ei = (const int*)d_in[1];   // [2, E] int32
    const float* W1 = (const float*)d_in[2];
    const float* b1 = (const float*)d_in[3];
    const float* W2 = (const float*)d_in[4];
    const float* b2 = (const float*)d_in[5];

    int N = in_sizes[0] / FD;
    int E = in_sizes[1] / 2;
    const int* src = ei;
    const int* dst = ei + E;
    int K = (N + (1 << BSH) - 1) >> BSH;     // buckets (<= 512 assumed)
    int PB = (E + CH - 1) / CH;              // partition blocks

    char* base = (char*)d_ws;
    size_t off = 0;
    auto align256 = [](size_t v) { return (v + 255) & ~(size_t)255; };
    int*            rp    = (int*)(base + off);            off += align256((size_t)(N + 1) * 4);
    float*          dis   = (float*)(base + off);          off += align256((size_t)N * 4);
    int*            total = (int*)(base + off);            off += align256(512 * 4);
    int*            deg   = (int*)(base + off);            off += align256((size_t)N * 4);
    int*            bbase = (int*)(base + off);            off += align256(513 * 4);
    unsigned short* w1t   = (unsigned short*)(base + off); off += align256((size_t)FD * FD * 2);
    unsigned short* w2t   = (unsigned short*)(base + off); off += align256((size_t)FD * FD * 2);
    int*            col   = (int*)(base + off);            off += align256((size_t)E * 4);
    unsigned short* hbuf  = (unsigned short*)(base + off); off += align256((size_t)N * FD * 2);
    unsigned short* z1    = (unsigned short*)(base + off); off += align256((size_t)N * FD * 2);
    int*            pairs = (int*)(base + off);            off += align256((size_t)E * 4);
    int*            lstartG = (int*)hbuf;   // overlay: dead before gemm1 (build launch) writes hbuf
    int*            lstartT = (int*)z1;     // overlay: dead before agg1 writes z1
    (void)ws_size; (void)n_in; (void)out_size;

    // total (2 KB) and deg (N*4) are adjacent -> single memset
    (void)hipMemsetAsync(total, 0, 2048 + (size_t)N * 4, stream);
    partition_kernel<<<PB + DB, 256, 0, stream>>>(src, dst, lstartG, total,
                                                  pairs, E, K, PB, deg);
    int nbx = (K + 1 + 31) / 32;
    int nby = (PB + 31) / 32;
    int nbt = nbx * nby;
    int ndis = (N + 511) / 512;
    trtot_kernel<<<nbt + 1 + ndis + 64, 512, 0, stream>>>(
        lstartG, lstartT, PB, K + 1, total, bbase, rp, K, E, N, nbx, nbt, ndis,
        deg, dis, W1, w1t, W2, w2t);

    int gemmGrid = (N + 127) / 128;
    build_kernel<<<K + gemmGrid, 256, 0, stream>>>(pairs, lstartT, bbase, rp,
                                                   col, N, PB, K,
                                                   x, w1t, dis, hbuf);

    dim3 aggBlk(64, 4);
    int aggGrid = (N + 3) / 4;

    agg_kernel<<<aggGrid, aggBlk, 0, stream>>>((const unsigned*)hbuf, dis, rp, col,
                                               (const float2*)b1, z1, N, 1);
    gemm_mfma_bf16<<<gemmGrid, 256, 0, stream>>>(z1, w2t, dis, hbuf, N);
    agg_kernel<<<aggGrid, aggBlk, 0, stream>>>((const unsigned*)hbuf, dis, rp, col,
                                               (const float2*)b2, d_out, N, 0);
}

// Round 13
// 252.426 us; speedup vs baseline: 1.1885x; 1.1885x over previous
//
#include <hip/hip_runtime.h>

#define FD 128      // feature dim (both layers)
#define BSH 7       // log2(nodes per bucket) = 128 nodes/bucket
#define CH 2048     // edges per partition block (782 blocks -> ~3/CU co-resident)
#define CHT 8       // edges per thread (CH / 256)
#define KMAX 512    // max buckets
#define SCAP 8192   // build_kernel LDS edge stage (mean bucket = 4092, max ~4400)
// packed pair: (local_dst << 17) | src   -- requires N <= 131072

typedef __attribute__((ext_vector_type(8))) short bf16x8;
typedef __attribute__((ext_vector_type(4))) float f32x4;

__device__ inline unsigned bfr(float f) {   // fp32 -> bf16 bits, round-nearest-even
    unsigned u = __float_as_uint(f);
    return (u + 0x7FFF + ((u >> 16) & 1)) >> 16;
}
__device__ inline float uplo(unsigned p) { return __uint_as_float(p << 16); }
__device__ inline float uphi(unsigned p) { return __uint_as_float(p & 0xFFFF0000u); }

// ---------------- CSR build ----------------
// R13 = R11 champion (245.4 us) + partition latency attack: CH back to 2048
// (782 blocks, ~3/CU -> 2x TLP for the barrier-serialized scan) and int4-
// vectorized edge loads / copy-out (4 edges per instruction on the per-block
// critical path). R12's deg-atomic fold reverted (cost ~35 us, measured).

__global__ __launch_bounds__(256) void partition_kernel(
        const int* __restrict__ src, const int* __restrict__ dst,
        int* __restrict__ lstartG, int* __restrict__ total,
        int* __restrict__ pairs, int E, int K) {
    __shared__ int lcnt[KMAX];     // counts, then scatter cursor
    __shared__ int lstart[KMAX];   // local exclusive prefix
    __shared__ int sm[256];
    __shared__ int staged[CH];
    int t = threadIdx.x;
    int base = blockIdx.x * CH;
    int n = min(CH, E - base);

    lcnt[t] = 0; lcnt[t + 256] = 0;
    __syncthreads();

    int pk[CHT]; int bn[CHT];
    #pragma unroll
    for (int j4 = 0; j4 < CHT / 4; ++j4) {
        int i = 4 * t + j4 * 1024;              // 4 consecutive edges / thread
        if (i + 3 < n) {
            int4 dv = *(const int4*)&dst[base + i];
            int4 sv = *(const int4*)&src[base + i];
            int dd[4] = {dv.x, dv.y, dv.z, dv.w};
            int ss[4] = {sv.x, sv.y, sv.z, sv.w};
            #pragma unroll
            for (int k = 0; k < 4; ++k) {
                int j = j4 * 4 + k;
                bn[j] = dd[k] >> BSH;
                pk[j] = ((dd[k] & ((1 << BSH) - 1)) << 17) | ss[k];
                atomicAdd(&lcnt[bn[j]], 1);
            }
        } else {
            #pragma unroll
            for (int k = 0; k < 4; ++k) {
                int j = j4 * 4 + k;
                bn[j] = -1;
                if (i + k < n) {
                    int d = dst[base + i + k];
                    int s = src[base + i + k];
                    bn[j] = d >> BSH;
                    pk[j] = ((d & ((1 << BSH) - 1)) << 17) | s;
                    atomicAdd(&lcnt[bn[j]], 1);
                }
            }
        }
    }
    __syncthreads();

    // exclusive scan of 512 bins, 2 consecutive bins per thread
    int c0 = lcnt[2 * t], c1 = lcnt[2 * t + 1];
    int s2 = c0 + c1;
    sm[t] = s2;
    __syncthreads();
    for (int off = 1; off < 256; off <<= 1) {
        int add = (t >= off) ? sm[t - off] : 0;
        __syncthreads();
        sm[t] += add;
        __syncthreads();
    }
    int ex = sm[t] - s2;
    lstart[2 * t] = ex;     lstart[2 * t + 1] = ex + c0;
    lcnt[2 * t]   = ex;     lcnt[2 * t + 1]   = ex + c0;   // cursor
    __syncthreads();

    // scatter chunk into staged[], sorted by bucket
    #pragma unroll
    for (int j = 0; j < CHT; ++j) {
        if (bn[j] >= 0) {
            int pos = atomicAdd(&lcnt[bn[j]], 1);
            staged[pos] = pk[j];
        }
    }
    __syncthreads();

    // vectorized coalesced copy-out: this block owns pairs[base .. base+n)
    for (int i = 4 * t; i < n; i += 1024) {
        if (i + 3 < n) {
            *(int4*)&pairs[base + i] = *(const int4*)&staged[i];
        } else {
            for (int k = 0; k < 4 && i + k < n; ++k)
                pairs[base + i + k] = staged[i + k];
        }
    }

    // per-block bucket boundaries + bucket totals
    size_t lrow = (size_t)blockIdx.x * (K + 1);
    for (int b = t; b < K; b += 256) {
        lstartG[lrow + b] = lstart[b];
        int c = lcnt[b] - lstart[b];
        if (c) atomicAdd(&total[b], c);
    }
    if (t == 0) lstartG[lrow + K] = n;
}

// merged: blocks [0, nbt) transpose lstartG [PB][K+1] -> lstartT [K+1][PB];
// last block does the 512-wide exclusive scan of total -> bbase (+ rp[N]=E).
__global__ __launch_bounds__(512) void trtot_kernel(
        const int* __restrict__ A, int* __restrict__ B, int R, int C,
        const int* __restrict__ total, int* __restrict__ bbase,
        int* __restrict__ rp, int K, int E, int N, int nbx) {
    __shared__ int tile[32][33];
    int t = threadIdx.x;
    if ((int)blockIdx.x == gridDim.x - 1) {      // totscan body
        __shared__ int sm[512];
        int v = (t < K) ? total[t] : 0;
        sm[t] = v;
        __syncthreads();
        for (int off = 1; off < 512; off <<= 1) {
            int add = (t >= off) ? sm[t - off] : 0;
            __syncthreads();
            sm[t] += add;
            __syncthreads();
        }
        if (t < K) bbase[t] = sm[t] - v;
        if (t == 0) { bbase[K] = E; rp[N] = E; }
        return;
    }
    int c0 = (blockIdx.x % nbx) * 32, r0 = (blockIdx.x / nbx) * 32;
    int tx = t & 31, ty = t >> 5;                // 512 threads: ty in [0,16)
    for (int i = ty; i < 32; i += 16) {
        int r = r0 + i, c = c0 + tx;
        if (r < R && c < C) tile[i][tx] = A[(size_t)r * C + c];
    }
    __syncthreads();
    for (int i = ty; i < 32; i += 16) {
        int c = c0 + i, r = r0 + tx;
        if (c < C && r < R) B[(size_t)c * R + r] = tile[tx][i];
    }
}

// Per-bucket (blocks < K): stage fragments into LDS with FUSED per-wave bin
// count, 512-entry scan ([bin][wave] bin-major), then scatter with per-wave
// cursors. Blocks >= K: weight transpose fp32->bf16 (wt fold, 64 blocks).
__global__ __launch_bounds__(256) void build_kernel(
        const int* __restrict__ pairs, const int* __restrict__ lstartT,
        const int* __restrict__ bbase, int* __restrict__ rp,
        float* __restrict__ dis, int* __restrict__ col, int N, int PB, int K,
        const float* __restrict__ W1, unsigned short* __restrict__ W1T,
        const float* __restrict__ W2, unsigned short* __restrict__ W2T) {
    __shared__ int staged[SCAP];
    __shared__ int lcnt[512];    // [bin*4+wave] counts, then absolute cursor
    __shared__ int pref[512];    // exclusive prefix (bucket-local)
    __shared__ int sm[256];
    int b = blockIdx.x;
    int t = threadIdx.x;

    if (b >= K) {                // wt fold: 64 blocks, 2 elems/thread
        int bb = b - K;
        #pragma unroll
        for (int rr = 0; rr < 2; ++rr) {
            int f = bb * 512 + rr * 256 + t;     // flat over 2*FD*FD = 32768
            int w = f >> 14, rm = f & 16383, k = rm >> 7, nn2 = rm & 127;
            const float* W = w ? W2 : W1;
            unsigned short* WT = w ? W2T : W1T;
            WT[nn2 * FD + k] = (unsigned short)bfr(W[k * FD + nn2]);
        }
        return;
    }

    int wv = t >> 6;
    int nbase = b << BSH;
    int nn = min(1 << BSH, N - nbase);
    int beg = bbase[b];
    int cnt = bbase[b + 1] - beg;

    // fragment descriptors (coalesced reads from transposed lstart; nf <= 4)
    int fp[4], fl0[4], flen[4];
    int nf = 0, mysum = 0;
    for (int p = t; p < PB; p += 256) {
        int l0 = lstartT[(size_t)b * PB + p];
        int l1 = lstartT[(size_t)(b + 1) * PB + p];
        fp[nf] = p; fl0[nf] = l0; flen[nf] = l1 - l0;
        mysum += l1 - l0;
        ++nf;
    }
    // exclusive scan of per-thread sums -> dest offsets in staged
    sm[t] = mysum;
    __syncthreads();
    for (int off = 1; off < 256; off <<= 1) {
        int add = (t >= off) ? sm[t - off] : 0;
        __syncthreads();
        sm[t] += add;
        __syncthreads();
    }
    int o = sm[t] - mysum;

    lcnt[t] = 0; lcnt[t + 256] = 0;
    __syncthreads();

    if (cnt <= SCAP) {   // fast path (always, for Poisson buckets)
        int oo = o;
        for (int f = 0; f < nf; ++f) {
            int gbase = fp[f] * CH + fl0[f];
            for (int i = 0; i < flen[f]; ++i) {
                int p = pairs[gbase + i];
                staged[oo + i] = p;
                atomicAdd(&lcnt[((p >> 17) << 2) | wv], 1);   // fused count
            }
            oo += flen[f];
        }
    } else {             // overflow fallback: count directly from global
        for (int f = 0; f < nf; ++f) {
            int gbase = fp[f] * CH + fl0[f];
            for (int i = 0; i < flen[f]; ++i)
                atomicAdd(&lcnt[((pairs[gbase + i] >> 17) << 2) | wv], 1);
        }
    }
    __syncthreads();

    // exclusive scan of 512 entries (bin-major: bin*4+wave), 2 per thread
    int c0 = lcnt[2 * t], c1 = lcnt[2 * t + 1];
    int s2 = c0 + c1;
    sm[t] = s2;
    __syncthreads();
    for (int off = 1; off < 256; off <<= 1) {
        int add = (t >= off) ? sm[t - off] : 0;
        __syncthreads();
        sm[t] += add;
        __syncthreads();
    }
    int ex = sm[t] - s2;
    pref[2 * t] = ex;  pref[2 * t + 1] = ex + c0;
    __syncthreads();

    // rp/dis per row (row start = plane-0 prefix; deg = row-range length)
    if (t < 128 && t < nn) {
        int rs = pref[t << 2];
        int re = (t < 127) ? pref[(t + 1) << 2] : cnt;
        rp[nbase + t] = beg + rs;
        dis[nbase + t] = rsqrtf((float)(re - rs + 1));  // deg incl. self-loop
    }
    // cursors (absolute)
    lcnt[2 * t]     = beg + pref[2 * t];
    lcnt[2 * t + 1] = beg + pref[2 * t + 1];
    __syncthreads();

    if (cnt <= SCAP) {
        int oo = o;
        for (int f = 0; f < nf; ++f) {
            for (int i = 0; i < flen[f]; ++i) {
                int p = staged[oo + i];
                int pos = atomicAdd(&lcnt[((p >> 17) << 2) | wv], 1);
                col[pos] = p & 0x1FFFF;
            }
            oo += flen[f];
        }
    } else {
        for (int f = 0; f < nf; ++f) {
            int gbase = fp[f] * CH + fl0[f];
            for (int i = 0; i < flen[f]; ++i) {
                int p = pairs[gbase + i];
                int pos = atomicAdd(&lcnt[((p >> 17) << 2) | wv], 1);
                col[pos] = p & 0x1FFFF;
            }
        }
    }
}

// ---------------- MFMA bf16 GEMM: C = bf16( dis[row] * (A @ W) ) ----------------
// R7-proven lean variant: only B staged in LDS; A fragments loaded directly
// from global (lane l16 = row, quad = k-octet -> clean 64 B sectors).

#define APAD 8
#define ASTR (FD + APAD)

template <bool A32>
__device__ void gemm_body(const void* __restrict__ Ap,
                          const unsigned short* __restrict__ WT,
                          const float* __restrict__ dis,
                          unsigned short* __restrict__ C, int M) {
    __shared__ unsigned short Bs[128 * ASTR];
    int tid = threadIdx.x;
    int lane = tid & 63;
    int wave = tid >> 6;
    int quad = lane >> 4;
    int l16 = lane & 15;
    int rowBase = blockIdx.x * 128;

    #pragma unroll
    for (int p = 0; p < 8; ++p) {
        int r = p * 16 + (tid >> 4);
        int cq = (tid & 15) * 8;
        *(uint4*)&Bs[r * ASTR + cq] = *(const uint4*)&WT[(size_t)r * FD + cq];
    }
    __syncthreads();

    int m0 = wave * 32;
    int r0 = rowBase + m0 + l16;        // a0 fragment row
    int r1 = r0 + 16;                   // a1 fragment row
    f32x4 acc[2][8] = {};
    #pragma unroll
    for (int kt = 0; kt < 4; ++kt) {
        int ko = kt * 32 + quad * 8;
        uint4 va = make_uint4(0u, 0u, 0u, 0u);
        uint4 vb = make_uint4(0u, 0u, 0u, 0u);
        if (A32) {
            const float* A = (const float*)Ap;
            if (r0 < M) {
                const float* a = A + (size_t)r0 * FD + ko;
                float4 f0 = *(const float4*)a;
                float4 f1 = *(const float4*)(a + 4);
                va.x = bfr(f0.x) | (bfr(f0.y) << 16);
                va.y = bfr(f0.z) | (bfr(f0.w) << 16);
                va.z = bfr(f1.x) | (bfr(f1.y) << 16);
                va.w = bfr(f1.z) | (bfr(f1.w) << 16);
            }
            if (r1 < M) {
                const float* a = A + (size_t)r1 * FD + ko;
                float4 f0 = *(const float4*)a;
                float4 f1 = *(const float4*)(a + 4);
                vb.x = bfr(f0.x) | (bfr(f0.y) << 16);
                vb.y = bfr(f0.z) | (bfr(f0.w) << 16);
                vb.z = bfr(f1.x) | (bfr(f1.y) << 16);
                vb.w = bfr(f1.z) | (bfr(f1.w) << 16);
            }
        } else {
            const unsigned short* A = (const unsigned short*)Ap;
            if (r0 < M) va = *(const uint4*)(A + (size_t)r0 * FD + ko);
            if (r1 < M) vb = *(const uint4*)(A + (size_t)r1 * FD + ko);
        }
        bf16x8 a0 = *(bf16x8*)&va;
        bf16x8 a1 = *(bf16x8*)&vb;
        #pragma unroll
        for (int n = 0; n < 8; ++n) {
            bf16x8 b = *(bf16x8*)&Bs[(n * 16 + l16) * ASTR + ko];
            acc[0][n] = __builtin_amdgcn_mfma_f32_16x16x32_bf16(a0, b, acc[0][n], 0, 0, 0);
            acc[1][n] = __builtin_amdgcn_mfma_f32_16x16x32_bf16(a1, b, acc[1][n], 0, 0, 0);
        }
    }

    #pragma unroll
    for (int ms = 0; ms < 2; ++ms) {
        #pragma unroll
        for (int r = 0; r < 4; ++r) {
            int grow = rowBase + m0 + ms * 16 + quad * 4 + r;
            if (grow < M) {
                float dv = dis[grow];
                #pragma unroll
                for (int n = 0; n < 8; ++n) {
                    C[(size_t)grow * FD + n * 16 + l16] =
                        (unsigned short)bfr(dv * acc[ms][n][r]);
                }
            }
        }
    }
}

__global__ __launch_bounds__(256) void gemm_mfma_f32(
        const float* __restrict__ A, const unsigned short* __restrict__ WT,
        const float* __restrict__ dis, unsigned short* __restrict__ C, int M) {
    gemm_body<true>(A, WT, dis, C, M);
}

__global__ __launch_bounds__(256) void gemm_mfma_bf16(
        const unsigned short* __restrict__ A, const unsigned short* __restrict__ WT,
        const float* __restrict__ dis, unsigned short* __restrict__ C, int M) {
    gemm_body<false>(A, WT, dis, C, M);
}

// ---------------- CSR aggregation + bias + ReLU ----------------
// Round-0 proven form (48.6 us floor, invariant across 7 designs) — UNCHANGED.

__global__ __launch_bounds__(256) void agg_kernel(
        const unsigned* __restrict__ h, const float* __restrict__ dis,
        const int* __restrict__ rp, const int* __restrict__ col,
        const float2* __restrict__ bias, void* __restrict__ out, int N, int obf) {
    int v = blockIdx.x * 4 + threadIdx.y;          // blockDim = (64, 4): wave per node
    v = __builtin_amdgcn_readfirstlane(v);         // wave-uniform -> scalar rp/col loads
    if (v >= N) return;
    int t = threadIdx.x;                           // 0..63
    float dv = dis[v];
    size_t vb = (size_t)v * 64 + t;
    unsigned hp = h[vb];                           // self term h'[v]
    float2 acc;
    acc.x = uplo(hp); acc.y = uphi(hp);
    int e = rp[v];
    int end = rp[v + 1];

    for (; e + 16 <= end; e += 16) {
        int u[16];
        #pragma unroll
        for (int j = 0; j < 16; ++j) u[j] = col[e + j];   // wave-uniform scalar loads
        unsigned p[16];
        #pragma unroll
        for (int j = 0; j < 16; ++j) p[j] = h[(size_t)u[j] * 64 + t];
        #pragma unroll
        for (int j = 0; j < 16; ++j) {
            acc.x += uplo(p[j]); acc.y += uphi(p[j]);
        }
    }
    for (; e + 4 <= end; e += 4) {
        int u0 = col[e], u1 = col[e + 1], u2 = col[e + 2], u3 = col[e + 3];
        unsigned p0 = h[(size_t)u0 * 64 + t];
        unsigned p1 = h[(size_t)u1 * 64 + t];
        unsigned p2 = h[(size_t)u2 * 64 + t];
        unsigned p3 = h[(size_t)u3 * 64 + t];
        acc.x += uplo(p0); acc.y += uphi(p0);
        acc.x += uplo(p1); acc.y += uphi(p1);
        acc.x += uplo(p2); acc.y += uphi(p2);
        acc.x += uplo(p3); acc.y += uphi(p3);
    }
    for (; e < end; ++e) {
        unsigned p = h[(size_t)col[e] * 64 + t];
        acc.x += uplo(p); acc.y += uphi(p);
    }

    float2 bb = bias[t];
    float2 r;
    r.x = fmaxf(fmaf(dv, acc.x, bb.x), 0.0f);
    r.y = fmaxf(fmaf(dv, acc.y, bb.y), 0.0f);
    if (obf) {
        ((unsigned*)out)[vb] = bfr(r.x) | (bfr(r.y) << 16);
    } else {
        ((float2*)out)[vb] = r;
    }
}

// ---------------- launch ----------------

extern "C" void kernel_launch(void* const* d_in, const int* in_sizes, int n_in,
                              void* d_out, int out_size, void* d_ws, size_t ws_size,
                              hipStream_t stream) {
    const float* x  = (const float*)d_in[0];
    const int*   ei = (const int*)d_in[1];   // [2, E] int32
    const float* W1 = (const float*)d_in[2];
    const float* b1 = (const float*)d_in[3];
    const float* W2 = (const float*)d_in[4];
    const float* b2 = (const float*)d_in[5];

    int N = in_sizes[0] / FD;
    int E = in_sizes[1] / 2;
    const int* src = ei;
    const int* dst = ei + E;
    int K = (N + (1 << BSH) - 1) >> BSH;     // buckets (<= 512 assumed)
    int PB = (E + CH - 1) / CH;              // partition blocks

    char* base = (char*)d_ws;
    size_t off = 0;
    auto align256 = [](size_t v) { return (v + 255) & ~(size_t)255; };
    int*            rp    = (int*)(base + off);            off += align256((size_t)(N + 1) * 4);
    float*          dis   = (float*)(base + off);          off += align256((size_t)N * 4);
    int*            total = (int*)(base + off);            off += align256(512 * 4);
    int*            bbase = (int*)(base + off);            off += align256(513 * 4);
    unsigned short* w1t   = (unsigned short*)(base + off); off += align256((size_t)FD * FD * 2);
    unsigned short* w2t   = (unsigned short*)(base + off); off += align256((size_t)FD * FD * 2);
    int*            col   = (int*)(base + off);            off += align256((size_t)E * 4);
    unsigned short* hbuf  = (unsigned short*)(base + off); off += align256((size_t)N * FD * 2);
    unsigned short* z1    = (unsigned short*)(base + off); off += align256((size_t)N * FD * 2);
    int*            pairs = (int*)(base + off);            off += align256((size_t)E * 4);
    int*            lstartG = (int*)hbuf;   // overlay: dead until gemm1 writes hbuf
    int*            lstartT = (int*)z1;     // overlay: dead until agg1 writes z1
    (void)ws_size; (void)n_in; (void)out_size;

    (void)hipMemsetAsync(total, 0, 512 * 4, stream);
    partition_kernel<<<PB, 256, 0, stream>>>(src, dst, lstartG, total, pairs, E, K);
    int nbx = (K + 1 + 31) / 32;
    int nby = (PB + 31) / 32;
    trtot_kernel<<<nbx * nby + 1, 512, 0, stream>>>(lstartG, lstartT, PB, K + 1,
                                                    total, bbase, rp, K, E, N, nbx);
    build_kernel<<<K + 64, 256, 0, stream>>>(pairs, lstartT, bbase, rp, dis, col,
                                             N, PB, K, W1, w1t, W2, w2t);

    dim3 aggBlk(64, 4);
    int aggGrid = (N + 3) / 4;
    int gemmGrid = (N + 127) / 128;

    gemm_mfma_f32 <<<gemmGrid, 256, 0, stream>>>(x, w1t, dis, hbuf, N);
    agg_kernel<<<aggGrid, aggBlk, 0, stream>>>((const unsigned*)hbuf, dis, rp, col,
                                               (const float2*)b1, z1, N, 1);
    gemm_mfma_bf16<<<gemmGrid, 256, 0, stream>>>(z1, w2t, dis, hbuf, N);
    agg_kernel<<<aggGrid, aggBlk, 0, stream>>>((const unsigned*)hbuf, dis, rp, col,
                                               (const float2*)b2, d_out, N, 0);
}

// Round 14
// 242.625 us; speedup vs baseline: 1.2366x; 1.0404x over previous
//
#include <hip/hip_runtime.h>

#define FD 128      // feature dim (both layers)
#define BSH 7       // log2(nodes per bucket) = 128 nodes/bucket
#define CH 4096     // edges per partition block (391 blocks)
#define CHT 16      // edges per thread (CH / 256)
#define KMAX 512    // max buckets
#define SCAP 8192   // build_kernel LDS edge stage (mean bucket = 4092, max ~4400)
// packed pair: (local_dst << 17) | src   -- requires N <= 131072

typedef __attribute__((ext_vector_type(8))) short bf16x8;
typedef __attribute__((ext_vector_type(4))) float f32x4;

__device__ inline unsigned bfr(float f) {   // fp32 -> bf16 bits, round-nearest-even
    unsigned u = __float_as_uint(f);
    return (u + 0x7FFF + ((u >> 16) & 1)) >> 16;
}
__device__ inline float uplo(unsigned p) { return __uint_as_float(p << 16); }
__device__ inline float uphi(unsigned p) { return __uint_as_float(p & 0xFFFF0000u); }

// ---------------- MFMA bf16 GEMM body (aliased-LDS pointer passed in) ------
// R7-proven lean variant: only B staged in LDS; A fragments loaded directly
// from global. SCALE=false: C = bf16(A @ W) (dis applied later in agg1).

#define APAD 8
#define ASTR (FD + APAD)

template <bool A32, bool SCALE>
__device__ void gemm_body(unsigned short* __restrict__ Bs,
                          const void* __restrict__ Ap,
                          const unsigned short* __restrict__ WT,
                          const float* __restrict__ dis,
                          unsigned short* __restrict__ C, int M, int blk) {
    int tid = threadIdx.x;
    int lane = tid & 63;
    int wave = tid >> 6;
    int quad = lane >> 4;
    int l16 = lane & 15;
    int rowBase = blk * 128;

    #pragma unroll
    for (int p = 0; p < 8; ++p) {
        int r = p * 16 + (tid >> 4);
        int cq = (tid & 15) * 8;
        *(uint4*)&Bs[r * ASTR + cq] = *(const uint4*)&WT[(size_t)r * FD + cq];
    }
    __syncthreads();

    int m0 = wave * 32;
    int r0 = rowBase + m0 + l16;        // a0 fragment row
    int r1 = r0 + 16;                   // a1 fragment row
    f32x4 acc[2][8] = {};
    #pragma unroll
    for (int kt = 0; kt < 4; ++kt) {
        int ko = kt * 32 + quad * 8;
        uint4 va = make_uint4(0u, 0u, 0u, 0u);
        uint4 vb = make_uint4(0u, 0u, 0u, 0u);
        if (A32) {
            const float* A = (const float*)Ap;
            if (r0 < M) {
                const float* a = A + (size_t)r0 * FD + ko;
                float4 f0 = *(const float4*)a;
                float4 f1 = *(const float4*)(a + 4);
                va.x = bfr(f0.x) | (bfr(f0.y) << 16);
                va.y = bfr(f0.z) | (bfr(f0.w) << 16);
                va.z = bfr(f1.x) | (bfr(f1.y) << 16);
                va.w = bfr(f1.z) | (bfr(f1.w) << 16);
            }
            if (r1 < M) {
                const float* a = A + (size_t)r1 * FD + ko;
                float4 f0 = *(const float4*)a;
                float4 f1 = *(const float4*)(a + 4);
                vb.x = bfr(f0.x) | (bfr(f0.y) << 16);
                vb.y = bfr(f0.z) | (bfr(f0.w) << 16);
                vb.z = bfr(f1.x) | (bfr(f1.y) << 16);
                vb.w = bfr(f1.z) | (bfr(f1.w) << 16);
            }
        } else {
            const unsigned short* A = (const unsigned short*)Ap;
            if (r0 < M) va = *(const uint4*)(A + (size_t)r0 * FD + ko);
            if (r1 < M) vb = *(const uint4*)(A + (size_t)r1 * FD + ko);
        }
        bf16x8 a0 = *(bf16x8*)&va;
        bf16x8 a1 = *(bf16x8*)&vb;
        #pragma unroll
        for (int n = 0; n < 8; ++n) {
            bf16x8 b = *(bf16x8*)&Bs[(n * 16 + l16) * ASTR + ko];
            acc[0][n] = __builtin_amdgcn_mfma_f32_16x16x32_bf16(a0, b, acc[0][n], 0, 0, 0);
            acc[1][n] = __builtin_amdgcn_mfma_f32_16x16x32_bf16(a1, b, acc[1][n], 0, 0, 0);
        }
    }

    #pragma unroll
    for (int ms = 0; ms < 2; ++ms) {
        #pragma unroll
        for (int r = 0; r < 4; ++r) {
            int grow = rowBase + m0 + ms * 16 + quad * 4 + r;
            if (grow < M) {
                float dv = SCALE ? dis[grow] : 1.0f;
                #pragma unroll
                for (int n = 0; n < 8; ++n) {
                    float val = SCALE ? (dv * acc[ms][n][r]) : acc[ms][n][r];
                    C[(size_t)grow * FD + n * 16 + l16] = (unsigned short)bfr(val);
                }
            }
        }
    }
}

// ---------------- precision prep (early launch; feeds gemm1 fold) ----------
__global__ void wt_kernel(const float* __restrict__ W1, unsigned short* __restrict__ W1T,
                          const float* __restrict__ W2, unsigned short* __restrict__ W2T) {
    int k = blockIdx.x & (FD - 1);
    int n = threadIdx.x;
    if (blockIdx.x < FD) W1T[n * FD + k] = (unsigned short)bfr(W1[k * FD + n]);
    else                 W2T[n * FD + k] = (unsigned short)bfr(W2[k * FD + n]);
}

// ---------------- fat launch: partition (blocks < PB) + gemm1 (rest) -------
// partition is latency-bound at ~1.5 blocks/CU (R12 PMC: VALUBusy 1.5%);
// gemm1 (needs only x, w1t) fills the idle CU slots. LDS aliased: gemm Bs
// 34816 B vs partition 21504 B -> 34.8 KB, 4 blocks/CU.
__global__ __launch_bounds__(256) void part_gemm_kernel(
        const int* __restrict__ src, const int* __restrict__ dst,
        int* __restrict__ lstartG, int* __restrict__ total,
        int* __restrict__ pairs, int E, int K, int PB,
        const float* __restrict__ x, const unsigned short* __restrict__ w1t,
        unsigned short* __restrict__ hbuf, int N) {
    __shared__ __align__(16) int smem[8704];   // 34816 B
    int t = threadIdx.x;

    if ((int)blockIdx.x >= PB) {               // gemm1 fold (unscaled output)
        gemm_body<true, false>((unsigned short*)smem, x, w1t, nullptr, hbuf,
                               N, (int)blockIdx.x - PB);
        return;
    }

    int* lcnt   = smem;          // KMAX: counts, then scatter cursor
    int* lstart = smem + 512;    // local exclusive prefix
    int* sm     = smem + 1024;   // 256
    int* staged = smem + 1280;   // CH = 4096

    int base = blockIdx.x * CH;
    int n = min(CH, E - base);

    lcnt[t] = 0; lcnt[t + 256] = 0;
    __syncthreads();

    int pk[CHT]; int bn[CHT];
    #pragma unroll
    for (int j = 0; j < CHT; ++j) {
        int i = t + j * 256;
        bn[j] = -1;
        if (i < n) {
            int d = dst[base + i];
            int s = src[base + i];
            bn[j] = d >> BSH;
            pk[j] = ((d & ((1 << BSH) - 1)) << 17) | s;
            atomicAdd(&lcnt[bn[j]], 1);
        }
    }
    __syncthreads();

    // exclusive scan of 512 bins, 2 consecutive bins per thread
    int c0 = lcnt[2 * t], c1 = lcnt[2 * t + 1];
    int s2 = c0 + c1;
    sm[t] = s2;
    __syncthreads();
    for (int off = 1; off < 256; off <<= 1) {
        int add = (t >= off) ? sm[t - off] : 0;
        __syncthreads();
        sm[t] += add;
        __syncthreads();
    }
    int ex = sm[t] - s2;
    lstart[2 * t] = ex;     lstart[2 * t + 1] = ex + c0;
    lcnt[2 * t]   = ex;     lcnt[2 * t + 1]   = ex + c0;   // cursor
    __syncthreads();

    // scatter chunk into staged[], sorted by bucket
    #pragma unroll
    for (int j = 0; j < CHT; ++j) {
        if (bn[j] >= 0) {
            int pos = atomicAdd(&lcnt[bn[j]], 1);
            staged[pos] = pk[j];
        }
    }
    __syncthreads();

    // sequential coalesced copy-out: this block owns pairs[base .. base+n)
    for (int i = t; i < n; i += 256)
        pairs[base + i] = staged[i];

    // per-block bucket boundaries + bucket totals
    size_t lrow = (size_t)blockIdx.x * (K + 1);
    for (int b = t; b < K; b += 256) {
        lstartG[lrow + b] = lstart[b];
        int c = lcnt[b] - lstart[b];
        if (c) atomicAdd(&total[b], c);
    }
    if (t == 0) lstartG[lrow + K] = n;
}

// merged: blocks [0, nbt) transpose lstartG [PB][K+1] -> lstartT [K+1][PB];
// last block does the 512-wide exclusive scan of total -> bbase (+ rp[N]=E).
__global__ __launch_bounds__(512) void trtot_kernel(
        const int* __restrict__ A, int* __restrict__ B, int R, int C,
        const int* __restrict__ total, int* __restrict__ bbase,
        int* __restrict__ rp, int K, int E, int N, int nbx) {
    __shared__ int tile[32][33];
    int t = threadIdx.x;
    if ((int)blockIdx.x == gridDim.x - 1) {      // totscan body
        __shared__ int sm[512];
        int v = (t < K) ? total[t] : 0;
        sm[t] = v;
        __syncthreads();
        for (int off = 1; off < 512; off <<= 1) {
            int add = (t >= off) ? sm[t - off] : 0;
            __syncthreads();
            sm[t] += add;
            __syncthreads();
        }
        if (t < K) bbase[t] = sm[t] - v;
        if (t == 0) { bbase[K] = E; rp[N] = E; }
        return;
    }
    int c0 = (blockIdx.x % nbx) * 32, r0 = (blockIdx.x / nbx) * 32;
    int tx = t & 31, ty = t >> 5;                // 512 threads: ty in [0,16)
    for (int i = ty; i < 32; i += 16) {
        int r = r0 + i, c = c0 + tx;
        if (r < R && c < C) tile[i][tx] = A[(size_t)r * C + c];
    }
    __syncthreads();
    for (int i = ty; i < 32; i += 16) {
        int c = c0 + i, r = r0 + tx;
        if (c < C && r < R) B[(size_t)c * R + r] = tile[tx][i];
    }
}

// Per-bucket: stage fragments into LDS with FUSED per-wave bin count,
// 512-entry scan ([bin][wave] bin-major), then scatter with per-wave cursors.
__global__ __launch_bounds__(256) void build_kernel(
        const int* __restrict__ pairs, const int* __restrict__ lstartT,
        const int* __restrict__ bbase, int* __restrict__ rp,
        float* __restrict__ dis, int* __restrict__ col, int N, int PB, int K) {
    __shared__ int staged[SCAP];
    __shared__ int lcnt[512];    // [bin*4+wave] counts, then absolute cursor
    __shared__ int pref[512];    // exclusive prefix (bucket-local)
    __shared__ int sm[256];
    int b = blockIdx.x;
    int t = threadIdx.x;
    int wv = t >> 6;
    int nbase = b << BSH;
    int nn = min(1 << BSH, N - nbase);
    int beg = bbase[b];
    int cnt = bbase[b + 1] - beg;

    // fragment descriptors (coalesced reads from transposed lstart; nf <= 2)
    int fp[2], fl0[2], flen[2];
    int nf = 0, mysum = 0;
    for (int p = t; p < PB; p += 256) {
        int l0 = lstartT[(size_t)b * PB + p];
        int l1 = lstartT[(size_t)(b + 1) * PB + p];
        fp[nf] = p; fl0[nf] = l0; flen[nf] = l1 - l0;
        mysum += l1 - l0;
        ++nf;
    }
    // exclusive scan of per-thread sums -> dest offsets in staged
    sm[t] = mysum;
    __syncthreads();
    for (int off = 1; off < 256; off <<= 1) {
        int add = (t >= off) ? sm[t - off] : 0;
        __syncthreads();
        sm[t] += add;
        __syncthreads();
    }
    int o = sm[t] - mysum;

    lcnt[t] = 0; lcnt[t + 256] = 0;
    __syncthreads();

    if (cnt <= SCAP) {   // fast path (always, for Poisson buckets)
        int oo = o;
        for (int f = 0; f < nf; ++f) {
            int gbase = fp[f] * CH + fl0[f];
            for (int i = 0; i < flen[f]; ++i) {
                int p = pairs[gbase + i];
                staged[oo + i] = p;
                atomicAdd(&lcnt[((p >> 17) << 2) | wv], 1);   // fused count
            }
            oo += flen[f];
        }
    } else {             // overflow fallback: count directly from global
        for (int f = 0; f < nf; ++f) {
            int gbase = fp[f] * CH + fl0[f];
            for (int i = 0; i < flen[f]; ++i)
                atomicAdd(&lcnt[((pairs[gbase + i] >> 17) << 2) | wv], 1);
        }
    }
    __syncthreads();

    // exclusive scan of 512 entries (bin-major: bin*4+wave), 2 per thread
    int c0 = lcnt[2 * t], c1 = lcnt[2 * t + 1];
    int s2 = c0 + c1;
    sm[t] = s2;
    __syncthreads();
    for (int off = 1; off < 256; off <<= 1) {
        int add = (t >= off) ? sm[t - off] : 0;
        __syncthreads();
        sm[t] += add;
        __syncthreads();
    }
    int ex = sm[t] - s2;
    pref[2 * t] = ex;  pref[2 * t + 1] = ex + c0;
    __syncthreads();

    // rp/dis per row (row start = plane-0 prefix; deg = row-range length)
    if (t < 128 && t < nn) {
        int rs = pref[t << 2];
        int re = (t < 127) ? pref[(t + 1) << 2] : cnt;
        rp[nbase + t] = beg + rs;
        dis[nbase + t] = rsqrtf((float)(re - rs + 1));  // deg incl. self-loop
    }
    // cursors (absolute)
    lcnt[2 * t]     = beg + pref[2 * t];
    lcnt[2 * t + 1] = beg + pref[2 * t + 1];
    __syncthreads();

    if (cnt <= SCAP) {
        int oo = o;
        for (int f = 0; f < nf; ++f) {
            for (int i = 0; i < flen[f]; ++i) {
                int p = staged[oo + i];
                int pos = atomicAdd(&lcnt[((p >> 17) << 2) | wv], 1);
                col[pos] = p & 0x1FFFF;
            }
            oo += flen[f];
        }
    } else {
        for (int f = 0; f < nf; ++f) {
            int gbase = fp[f] * CH + fl0[f];
            for (int i = 0; i < flen[f]; ++i) {
                int p = pairs[gbase + i];
                int pos = atomicAdd(&lcnt[((p >> 17) << 2) | wv], 1);
                col[pos] = p & 0x1FFFF;
            }
        }
    }
}

__global__ __launch_bounds__(256) void gemm_mfma_bf16(
        const unsigned short* __restrict__ A, const unsigned short* __restrict__ WT,
        const float* __restrict__ dis, unsigned short* __restrict__ C, int M) {
    __shared__ __align__(16) unsigned short Bs[128 * ASTR];
    gemm_body<false, true>(Bs, A, WT, dis, C, M, blockIdx.x);
}

// ---------------- CSR aggregation + bias + ReLU ----------------
// Round-0 proven structure. ESCALE=1 (agg1): h rows are UNSCALED bf16(xW1);
// per-edge dis[u] applied via wave-uniform sgpr fma operand (same VALU count
// as the add it replaces; +16 s_loads per batch). ESCALE=0 (agg2): original
// byte-identical path (h pre-scaled by gemm2).

template <bool ESCALE>
__device__ void agg_body(const unsigned* __restrict__ h, const float* __restrict__ dis,
                         const int* __restrict__ rp, const int* __restrict__ col,
                         const float2* __restrict__ bias, void* __restrict__ out,
                         int N, int obf) {
    int v = blockIdx.x * 4 + threadIdx.y;          // blockDim = (64, 4): wave per node
    v = __builtin_amdgcn_readfirstlane(v);         // wave-uniform -> scalar rp/col loads
    if (v >= N) return;
    int t = threadIdx.x;                           // 0..63
    float dv = dis[v];
    size_t vb = (size_t)v * 64 + t;
    unsigned hp = h[vb];                           // self term
    float2 acc;
    if (ESCALE) { acc.x = dv * uplo(hp); acc.y = dv * uphi(hp); }
    else        { acc.x = uplo(hp);      acc.y = uphi(hp); }
    int e = rp[v];
    int end = rp[v + 1];

    for (; e + 16 <= end; e += 16) {
        int u[16];
        #pragma unroll
        for (int j = 0; j < 16; ++j) u[j] = col[e + j];   // wave-uniform scalar loads
        float du[16];
        if (ESCALE) {
            #pragma unroll
            for (int j = 0; j < 16; ++j) du[j] = dis[u[j]];
        }
        unsigned p[16];
        #pragma unroll
        for (int j = 0; j < 16; ++j) p[j] = h[(size_t)u[j] * 64 + t];
        #pragma unroll
        for (int j = 0; j < 16; ++j) {
            if (ESCALE) {
                acc.x = fmaf(du[j], uplo(p[j]), acc.x);
                acc.y = fmaf(du[j], uphi(p[j]), acc.y);
            } else {
                acc.x += uplo(p[j]); acc.y += uphi(p[j]);
            }
        }
    }
    for (; e + 4 <= end; e += 4) {
        int u0 = col[e], u1 = col[e + 1], u2 = col[e + 2], u3 = col[e + 3];
        unsigned p0 = h[(size_t)u0 * 64 + t];
        unsigned p1 = h[(size_t)u1 * 64 + t];
        unsigned p2 = h[(size_t)u2 * 64 + t];
        unsigned p3 = h[(size_t)u3 * 64 + t];
        if (ESCALE) {
            float d0 = dis[u0], d1 = dis[u1], d2 = dis[u2], d3 = dis[u3];
            acc.x = fmaf(d0, uplo(p0), acc.x); acc.y = fmaf(d0, uphi(p0), acc.y);
            acc.x = fmaf(d1, uplo(p1), acc.x); acc.y = fmaf(d1, uphi(p1), acc.y);
            acc.x = fmaf(d2, uplo(p2), acc.x); acc.y = fmaf(d2, uphi(p2), acc.y);
            acc.x = fmaf(d3, uplo(p3), acc.x); acc.y = fmaf(d3, uphi(p3), acc.y);
        } else {
            acc.x += uplo(p0); acc.y += uphi(p0);
            acc.x += uplo(p1); acc.y += uphi(p1);
            acc.x += uplo(p2); acc.y += uphi(p2);
            acc.x += uplo(p3); acc.y += uphi(p3);
        }
    }
    for (; e < end; ++e) {
        int u0 = col[e];
        unsigned p = h[(size_t)u0 * 64 + t];
        if (ESCALE) {
            float d0 = dis[u0];
            acc.x = fmaf(d0, uplo(p), acc.x); acc.y = fmaf(d0, uphi(p), acc.y);
        } else {
            acc.x += uplo(p); acc.y += uphi(p);
        }
    }

    float2 bb = bias[t];
    float2 r;
    r.x = fmaxf(fmaf(dv, acc.x, bb.x), 0.0f);
    r.y = fmaxf(fmaf(dv, acc.y, bb.y), 0.0f);
    if (obf) {
        ((unsigned*)out)[vb] = bfr(r.x) | (bfr(r.y) << 16);
    } else {
        ((float2*)out)[vb] = r;
    }
}

__global__ __launch_bounds__(256) void agg_kernel_e(
        const unsigned* __restrict__ h, const float* __restrict__ dis,
        const int* __restrict__ rp, const int* __restrict__ col,
        const float2* __restrict__ bias, void* __restrict__ out, int N, int obf) {
    agg_body<true>(h, dis, rp, col, bias, out, N, obf);
}

__global__ __launch_bounds__(256) void agg_kernel(
        const unsigned* __restrict__ h, const float* __restrict__ dis,
        const int* __restrict__ rp, const int* __restrict__ col,
        const float2* __restrict__ bias, void* __restrict__ out, int N, int obf) {
    agg_body<false>(h, dis, rp, col, bias, out, N, obf);
}

// ---------------- launch ----------------

extern "C" void kernel_launch(void* const* d_in, const int* in_sizes, int n_in,
                              void* d_out, int out_size, void* d_ws, size_t ws_size,
                              hipStream_t stream) {
    const float* x  = (const float*)d_in[0];
    const int*   ei = (const int*)d_in[1];   // [2, E] int32
    const float* W1 = (const float*)d_in[2];
    const float* b1 = (const float*)d_in[3];
    const float* W2 = (const float*)d_in[4];
    const float* b2 = (const float*)d_in[5];

    int N = in_sizes[0] / FD;
    int E = in_sizes[1] / 2;
    const int* src = ei;
    const int* dst = ei + E;
    int K = (N + (1 << BSH) - 1) >> BSH;     // buckets (<= 512 assumed)
    int PB = (E + CH - 1) / CH;              // partition blocks

    char* base = (char*)d_ws;
    size_t off = 0;
    auto align256 = [](size_t v) { return (v + 255) & ~(size_t)255; };
    int*            rp    = (int*)(base + off);            off += align256((size_t)(N + 1) * 4);
    float*          dis   = (float*)(base + off);          off += align256((size_t)N * 4);
    int*            total = (int*)(base + off);            off += align256(512 * 4);
    int*            bbase = (int*)(base + off);            off += align256(513 * 4);
    unsigned short* w1t   = (unsigned short*)(base + off); off += align256((size_t)FD * FD * 2);
    unsigned short* w2t   = (unsigned short*)(base + off); off += align256((size_t)FD * FD * 2);
    int*            col   = (int*)(base + off);            off += align256((size_t)E * 4);
    unsigned short* hbuf  = (unsigned short*)(base + off); off += align256((size_t)N * FD * 2);
    unsigned short* z1    = (unsigned short*)(base + off); off += align256((size_t)N * FD * 2);
    int*            pairs = (int*)(base + off);            off += align256((size_t)E * 4);
    int*            lstartG = (int*)(base + off);          off += align256((size_t)PB * (K + 1) * 4);
    int*            lstartT = (int*)z1;     // overlay: dead before agg1 writes z1
    (void)ws_size; (void)n_in; (void)out_size;

    (void)hipMemsetAsync(total, 0, 512 * 4, stream);
    wt_kernel<<<2 * FD, FD, 0, stream>>>(W1, w1t, W2, w2t);

    int gemmGrid = (N + 127) / 128;
    part_gemm_kernel<<<PB + gemmGrid, 256, 0, stream>>>(
        src, dst, lstartG, total, pairs, E, K, PB, x, w1t, hbuf, N);

    int nbx = (K + 1 + 31) / 32;
    int nby = (PB + 31) / 32;
    trtot_kernel<<<nbx * nby + 1, 512, 0, stream>>>(lstartG, lstartT, PB, K + 1,
                                                    total, bbase, rp, K, E, N, nbx);
    build_kernel<<<K, 256, 0, stream>>>(pairs, lstartT, bbase, rp, dis, col,
                                        N, PB, K);

    dim3 aggBlk(64, 4);
    int aggGrid = (N + 3) / 4;

    agg_kernel_e<<<aggGrid, aggBlk, 0, stream>>>((const unsigned*)hbuf, dis, rp, col,
                                                 (const float2*)b1, z1, N, 1);
    gemm_mfma_bf16<<<gemmGrid, 256, 0, stream>>>(z1, w2t, dis, hbuf, N);
    agg_kernel<<<aggGrid, aggBlk, 0, stream>>>((const unsigned*)hbuf, dis, rp, col,
                                               (const float2*)b2, d_out, N, 0);
}